// Round 4
// baseline (181.448 us; speedup 1.0000x reference)
//
#include <hip/hip_runtime.h>

#define B_ 16
#define N_ 4096
#define C_ 256
#define K_ 8
#define EPS 1e-6f
#define RATIO 0.1f

typedef float f32x4 __attribute__((ext_vector_type(4)));
typedef __bf16 bf16x8 __attribute__((ext_vector_type(8)));

__device__ inline unsigned short f2bf(float f){
  unsigned int u = __float_as_uint(f);
  u += 0x7FFFu + ((u >> 16) & 1u);   // RNE
  return (unsigned short)(u >> 16);
}
__device__ inline float bf2f(unsigned short h){
  return __uint_as_float(((unsigned int)h) << 16);
}

union BFu { ushort4 u4[2]; bf16x8 v; };

// ---------------- K0: init ws, W1 -> frag-swizzled bf16, Wg hi/lo, geno logits
// W1swz flat index: (((k*16 + nt)*8 + s)*64 + lane)*8 + e
//   holds W1[k][nt*16 + (lane&15)][s*32 + (lane>>4)*8 + e]
__global__ __launch_bounds__(256) void k0_prep(
    const float* __restrict__ W1, const float* __restrict__ Wg,
    const float* __restrict__ geno, const float* __restrict__ Wgg,
    const float* __restrict__ bgg,
    unsigned short* __restrict__ W1swz,
    unsigned short* __restrict__ Wgp_hi, unsigned short* __restrict__ Wgp_lo,
    int* __restrict__ cnt,
    float* __restrict__ mass, float* __restrict__ conf,
    float* __restrict__ glog)
{
  int gid = blockIdx.x * 256 + threadIdx.x;           // 65536 threads
  if (gid < B_*K_) { cnt[gid] = 0; mass[gid] = 0.f; }
  if (gid == 0) conf[0] = 0.f;
  {
    int o = gid << 3;                                  // 8 elements per thread
    int lane6 = (o >> 3) & 63;
    int s  = (o >> 9) & 7;
    int nt = (o >> 12) & 15;
    int k  = o >> 16;
    int quad = lane6 >> 4, l16 = lane6 & 15;
    int j  = nt*16 + l16;
    int c0 = s*32 + quad*8;
    const float* src = W1 + (k << 16) + (j << 8) + c0;
    unsigned short* dst = W1swz + o;
    #pragma unroll
    for (int e = 0; e < 8; ++e) dst[e] = f2bf(src[e]);
  }
  if (gid < 16*C_){
    int r = gid >> 8, c = gid & 255;
    float v = (r < K_) ? Wg[(r << 8) + c] : 0.f;
    unsigned short h = f2bf(v);
    Wgp_hi[gid] = h;
    Wgp_lo[gid] = f2bf(v - bf2f(h));
  }
  int wv = gid >> 6;
  if (wv < B_*K_){
    int lane = threadIdx.x & 63;
    int b = wv >> 3, k = wv & 7;
    float4 a = *(const float4*)(geno + b*C_ + lane*4);
    float4 w = *(const float4*)(Wgg  + k*C_ + lane*4);
    float p = a.x*w.x + a.y*w.y + a.z*w.z + a.w*w.w;
    #pragma unroll
    for (int off = 32; off; off >>= 1) p += __shfl_xor(p, off);
    if (lane == 0) glog[wv] = RATIO * (p + bgg[k]);
  }
}

// ---------------- K1 (R11): hoisted loads (16 in flight), 4-wave phase-2 -----
__global__ __launch_bounds__(256) void k1_gate(
    const float* __restrict__ tokens,
    const unsigned short* __restrict__ Wgp_hi, const unsigned short* __restrict__ Wgp_lo,
    const float* __restrict__ bg, const float* __restrict__ glog,
    int* __restrict__ cnt, int* __restrict__ bidx, float* __restrict__ bw,
    float* __restrict__ mass, float* __restrict__ conf,
    unsigned short* __restrict__ tok_bf)
{
  __shared__ float ls[64][9];              // logits, +1 pad
  __shared__ float bg_s[K_], gl_s[K_], mass_s[K_];
  __shared__ int lcnt[K_], gbase[K_];
  __shared__ int e0s[64], e1s[64], s0s[64], s1s[64];
  __shared__ float w0s[64], w1s[64];
  __shared__ float cred[4];
  int tid = threadIdx.x, lane = tid & 63, wave = tid >> 6;
  int quad = lane >> 4, l16 = lane & 15;
  int b = blockIdx.x >> 6;
  int tok0 = (blockIdx.x & 63) * 64;
  if (tid < K_){ bg_s[tid] = bg[tid]; gl_s[tid] = glog[b*K_ + tid];
                 mass_s[tid] = 0.f; lcnt[tid] = 0; }
  __syncthreads();

  // phase 1: logits via 3-term split-precision MFMA; emit bf16 tokens.
  // ALL 16 token loads hoisted -> in flight together (VGPR=20 JIT-load fix).
  {
    int trow = tok0 + wave*16 + l16;
    const float* xsrc = tokens + ((size_t)b*N_ + trow)*C_ + quad*8;
    unsigned short* bdst = tok_bf + (((size_t)(b*N_ + trow)) << 8) + quad*8;
    float4 xa[8], xb[8];
    #pragma unroll
    for (int s = 0; s < 8; ++s){
      xa[s] = *(const float4*)(xsrc + s*32);
      xb[s] = *(const float4*)(xsrc + s*32 + 4);
    }
    f32x4 acc; acc.x = 0.f; acc.y = 0.f; acc.z = 0.f; acc.w = 0.f;
    #pragma unroll
    for (int s = 0; s < 8; ++s){
      BFu hi, lo;
      hi.u4[0].x = f2bf(xa[s].x); hi.u4[0].y = f2bf(xa[s].y);
      hi.u4[0].z = f2bf(xa[s].z); hi.u4[0].w = f2bf(xa[s].w);
      hi.u4[1].x = f2bf(xb[s].x); hi.u4[1].y = f2bf(xb[s].y);
      hi.u4[1].z = f2bf(xb[s].z); hi.u4[1].w = f2bf(xb[s].w);
      lo.u4[0].x = f2bf(xa[s].x - bf2f(hi.u4[0].x));
      lo.u4[0].y = f2bf(xa[s].y - bf2f(hi.u4[0].y));
      lo.u4[0].z = f2bf(xa[s].z - bf2f(hi.u4[0].z));
      lo.u4[0].w = f2bf(xa[s].w - bf2f(hi.u4[0].w));
      lo.u4[1].x = f2bf(xb[s].x - bf2f(hi.u4[1].x));
      lo.u4[1].y = f2bf(xb[s].y - bf2f(hi.u4[1].y));
      lo.u4[1].z = f2bf(xb[s].z - bf2f(hi.u4[1].z));
      lo.u4[1].w = f2bf(xb[s].w - bf2f(hi.u4[1].w));
      *(ushort4*)(bdst + s*32)     = hi.u4[0];
      *(ushort4*)(bdst + s*32 + 4) = hi.u4[1];
      bf16x8 bhi = *(const bf16x8*)(Wgp_hi + l16*C_ + s*32 + quad*8);
      bf16x8 blo = *(const bf16x8*)(Wgp_lo + l16*C_ + s*32 + quad*8);
      acc = __builtin_amdgcn_mfma_f32_16x16x32_bf16(hi.v, bhi, acc, 0, 0, 0);
      acc = __builtin_amdgcn_mfma_f32_16x16x32_bf16(lo.v, bhi, acc, 0, 0, 0);
      acc = __builtin_amdgcn_mfma_f32_16x16x32_bf16(hi.v, blo, acc, 0, 0, 0);
    }
    if (l16 < K_){
      #pragma unroll
      for (int rr = 0; rr < 4; ++rr){
        int tl = wave*16 + quad*4 + rr;     // D row = quad*4+reg
        ls[tl][l16] = acc[rr] + bg_s[l16] + gl_s[l16];
      }
    }
  }
  __syncthreads();

  // phase 2: per-token top-2 + softmax + compaction, PARALLEL across 4 waves
  // (token t = wave*16 + l16, active lanes quad==0 -> 4x shorter serial path)
  if (quad == 0){
    int t = (wave << 4) | l16;
    float v0 = -1e30f, v1 = -1e30f; int i0 = 0, i1 = 0;
    #pragma unroll
    for (int kk = 0; kk < K_; ++kk){
      float l = ls[t][kk];
      if (l > v0){ v1 = v0; i1 = i0; v0 = l; i0 = kk; }
      else if (l > v1){ v1 = l; i1 = kk; }
    }
    float e  = expf(v1 - v0);
    float w0 = 1.f / (1.f + e), w1 = e / (1.f + e);
    w0 = fmaxf(w0, EPS); w1 = fmaxf(w1, EPS);
    float inv = 1.f / (w0 + w1);
    w0 *= inv; w1 *= inv;
    int p0 = atomicAdd(&lcnt[i0], 1);
    int p1 = atomicAdd(&lcnt[i1], 1);
    e0s[t] = i0; e1s[t] = i1; s0s[t] = p0; s1s[t] = p1;
    w0s[t] = w0; w1s[t] = w1;
    atomicAdd(&mass_s[i0], w0);
    atomicAdd(&mass_s[i1], w1);
    float ca = v0 - v1;                    // reduce over 16 active lanes
    #pragma unroll
    for (int off = 8; off; off >>= 1) ca += __shfl_down(ca, off);
    if (l16 == 0) cred[wave] = ca;
  }
  __syncthreads();
  if (tid < K_){                            // one global RMW per expert per block
    gbase[tid] = atomicAdd(&cnt[b*K_ + tid], lcnt[tid]);
    atomicAdd(&mass[b*K_ + tid], mass_s[tid]);
  }
  if (tid == 0) atomicAdd(conf, cred[0] + cred[1] + cred[2] + cred[3]);
  __syncthreads();
  if (quad == 0){
    int t = (wave << 4) | l16;
    int n = tok0 + t;
    int ke0 = e0s[t], ke1 = e1s[t];
    size_t o0 = (size_t)(b*K_ + ke0)*N_ + gbase[ke0] + s0s[t];
    size_t o1 = (size_t)(b*K_ + ke1)*N_ + gbase[ke1] + s1s[t];
    bidx[o0] = n;  bw[o0] = w0s[t];
    bidx[o1] = n;  bw[o1] = w1s[t];
  }
}

// ---------------- K4 (R11): depth-3 prefetch (6-region ring), 1-batch/XCD ----
// One block per (bucket, 128-token chunk). 16 tiles of 8 KB through a 6-region
// LDS ring, 3 tiles in flight across barriers (vmcnt(6)); raw s_barrier (no
// drain). Ring safety: stage(p+3)->region (p+3)%6; slowest wave pre-barrier(p)
// is in compute(p-1) using region (p-1)%6 != (p+3)%6.
// XCD swizzle: each XCD owns ONE batch per half -> L2 set = 1 MB W1swz +
// 2 MB tok_bf slab = 3 MB < 4 MB L2 (R3's 5 MB set thrashed -> L3 latency).
#define K4_STAGE(T, REG) do {                                                  \
    _Pragma("unroll")                                                          \
    for (int i = 0; i < 2; ++i){                                               \
      int c16 = (T)*512 + i*256 + tid;                                         \
      __builtin_amdgcn_global_load_lds(                                        \
        (const __attribute__((address_space(1))) unsigned int*)(wsrc + c16*8), \
        (__attribute__((address_space(3))) unsigned int*)(&Bs[REG][0] + (i*256 + tid)*8), \
        16, 0, 0);                                                             \
    }                                                                          \
  } while(0)

__global__ __launch_bounds__(256, 3) void k4_expert(
    const unsigned short* __restrict__ tok_bf, const unsigned short* __restrict__ W1swz,
    const float* __restrict__ b1, const int* __restrict__ cnt,
    const int* __restrict__ bidx, const float* __restrict__ bw,
    float* __restrict__ gpart)
{
  int lin = blockIdx.x;                    // 0..4095
  int halfg = lin >> 11;                   // 0,1
  int l2i = lin & 2047;
  int w = (halfg << 11) | ((l2i & 7) << 8) | (l2i >> 3);   // XCD x -> batch x(+8)
  int bat = w >> 8;
  int k = (w >> 5) & 7;
  int chunk = w & 31;
  int bucket = (bat << 3) | k;
  int M = cnt[bucket];
  if (chunk * 128 >= M) return;
  int Mm1 = M - 1;

  __shared__ unsigned short Bs[6][4096];   // 48 KB: 6-region ring, 8 KB tiles
  __shared__ float wtok[128];
  __shared__ float red[2][4][16];

  int tid = threadIdx.x, lane = tid & 63, wave = tid >> 6;
  int quad = lane >> 4, l16 = lane & 15;
  int bwbase = bucket << 12;               // bucket * N_

  const unsigned short* wsrc = W1swz + ((size_t)k << 16);

  // prologue: stage tiles 0,1,2
  K4_STAGE(0, 0);
  K4_STAGE(1, 1);
  K4_STAGE(2, 2);

  if (tid < 128){
    int tn = chunk*128 + tid;
    wtok[tid] = (tn < M) ? bw[bwbase + tn] : 0.f;
  }

  // gather A fragments once; reused across all 16 tiles
  int r0 = chunk*128 + (wave << 4) + l16;
  int nn0 = bidx[bwbase + min(r0, Mm1)];
  int nn1 = bidx[bwbase + min(r0 + 64, Mm1)];
  const unsigned short* p0 = tok_bf + (((size_t)((bat << 12) + nn0)) << 8) + (quad << 3);
  const unsigned short* p1 = tok_bf + (((size_t)((bat << 12) + nn1)) << 8) + (quad << 3);
  bf16x8 a0[8], a1[8];
  #pragma unroll
  for (int s = 0; s < 8; ++s){
    a0[s] = *(const bf16x8*)(p0 + s*32);
    a1[s] = *(const bf16x8*)(p1 + s*32);
  }

  float bias[16];
  #pragma unroll
  for (int p = 0; p < 16; ++p) bias[p] = b1[(k << 8) + (p << 4) + l16];

  float* gdst = gpart + (size_t)(((bucket << 5) + chunk) << 8);
  int wq = (wave << 4) + (quad << 2);

  #pragma unroll
  for (int p = 0; p < 16; ++p){
    if (p <= 12) K4_STAGE(p + 3, (p + 3) % 6);
    if (p <= 12){
      asm volatile("s_waitcnt vmcnt(6) lgkmcnt(0)" ::: "memory");
    } else if (p == 13){
      asm volatile("s_waitcnt vmcnt(4) lgkmcnt(0)" ::: "memory");
    } else if (p == 14){
      asm volatile("s_waitcnt vmcnt(2) lgkmcnt(0)" ::: "memory");
    } else {
      asm volatile("s_waitcnt vmcnt(0) lgkmcnt(0)" ::: "memory");
    }
    __builtin_amdgcn_s_barrier();

    if (p > 0 && tid < 16){                // tile p-1 cross-wave sum + store
      int pb = (p - 1) & 1;
      float sv = red[pb][0][tid] + red[pb][1][tid]
               + red[pb][2][tid] + red[pb][3][tid];
      gdst[((p - 1) << 4) + tid] = sv;
    }

    f32x4 acc0, acc1;
    acc0.x=0.f; acc0.y=0.f; acc0.z=0.f; acc0.w=0.f;
    acc1.x=0.f; acc1.y=0.f; acc1.z=0.f; acc1.w=0.f;
    #pragma unroll
    for (int s = 0; s < 8; ++s){
      bf16x8 bb = *(const bf16x8*)(&Bs[p % 6][0] + ((s*64 + lane) << 3));
      acc0 = __builtin_amdgcn_mfma_f32_16x16x32_bf16(a0[s], bb, acc0, 0, 0, 0);
      acc1 = __builtin_amdgcn_mfma_f32_16x16x32_bf16(a1[s], bb, acc1, 0, 0, 0);
    }
    float pt = 0.f;
    #pragma unroll
    for (int rr = 0; rr < 4; ++rr){
      float h0 = fmaxf(acc0[rr] + bias[p], 0.f);
      float h1 = fmaxf(acc1[rr] + bias[p], 0.f);
      pt += wtok[wq + rr] * h0 + wtok[64 + wq + rr] * h1;
    }
    pt += __shfl_down(pt, 32);
    pt += __shfl_down(pt, 16);
    if (lane < 16) red[p & 1][wave][lane] = pt;
  }
  asm volatile("s_waitcnt lgkmcnt(0)" ::: "memory");
  __builtin_amdgcn_s_barrier();
  if (tid < 16){                           // tail: tile 15
    float sv = red[1][0][tid] + red[1][1][tid] + red[1][2][tid] + red[1][3][tid];
    gdst[(15 << 4) + tid] = sv;
  }
}

// ---------------- K5: reduce chunk partials + layer-2 + divide by mass
//                  (+ fused scalars: lb_loss & routing confidence) -----------
__global__ __launch_bounds__(256) void k5_centers(
    const float* __restrict__ gpart, const int* __restrict__ cnt,
    const float* __restrict__ W2, const float* __restrict__ b2,
    const float* __restrict__ mass, const float* __restrict__ conf,
    float* __restrict__ out)
{
  __shared__ float gv[C_];
  int z = blockIdx.x, tid = threadIdx.x;
  int k = z & 7;
  int nch = (cnt[z] + 127) >> 7;
  float sv = 0.f;
  for (int c = 0; c < nch; ++c)
    sv += gpart[(size_t)((((z << 5) + c) << 8) + tid)];
  gv[tid] = sv;
  __syncthreads();
  float m = mass[z];
  float inv = 1.f / fmaxf(m, EPS);
  int tq = tid & 3, cb = tid >> 2;
  #pragma unroll 1
  for (int h = 0; h < 2; ++h){
    int c = (blockIdx.y*2 + h)*64 + cb;
    const float4* wrow = (const float4*)(W2 + ((((k << 8) + c)) << 8));
    float dot = 0.f;
    #pragma unroll
    for (int jj = 0; jj < 16; ++jj){
      float4 w4 = wrow[jj*4 + tq];
      float4 g4 = *(const float4*)&gv[(jj*4 + tq) * 4];
      dot += w4.x*g4.x + w4.y*g4.y + w4.z*g4.z + w4.w*g4.w;
    }
    dot += __shfl_xor(dot, 1);
    dot += __shfl_xor(dot, 2);
    if (tq == 0) out[z*C_ + c] = (dot + m * b2[k*C_ + c]) * inv;
  }
  if (z == 0 && blockIdx.y == 0 && tid == 0){   // fused k2 (single thread)
    float u[K_];
    #pragma unroll
    for (int kk = 0; kk < K_; ++kk) u[kk] = 0.f;
    for (int i = 0; i < B_*K_; ++i) u[i & 7] += (float)cnt[i];
    float mean = 0.f;
    #pragma unroll
    for (int kk = 0; kk < K_; ++kk){ u[kk] *= (1.f / (float)(B_*N_)); mean += u[kk]; }
    mean *= (1.f / K_);
    float var = 0.f;
    #pragma unroll
    for (int kk = 0; kk < K_; ++kk){ float d = u[kk] - mean; var += d*d; }
    var *= (1.f / K_);
    float denom = mean + EPS;
    out[B_*K_*C_]     = var / (denom * denom);
    out[B_*K_*C_ + 1] = conf[0] / (float)(B_*N_);
  }
}

extern "C" void kernel_launch(void* const* d_in, const int* in_sizes, int n_in,
                              void* d_out, int out_size, void* d_ws, size_t ws_size,
                              hipStream_t stream)
{
  const float* tokens = (const float*)d_in[0];
  const float* geno   = (const float*)d_in[1];
  const float* Wg     = (const float*)d_in[2];
  const float* bg     = (const float*)d_in[3];
  const float* Wgg    = (const float*)d_in[4];
  const float* bgg    = (const float*)d_in[5];
  const float* W1     = (const float*)d_in[6];
  const float* b1     = (const float*)d_in[7];
  const float* W2     = (const float*)d_in[8];
  const float* b2     = (const float*)d_in[9];
  float* out = (float*)d_out;
  char* ws = (char*)d_ws;
  unsigned short* W1swz  = (unsigned short*)(ws);              // 1,048,576
  unsigned short* Wgp_hi = (unsigned short*)(ws + 1048576);    //     8,192
  unsigned short* Wgp_lo = (unsigned short*)(ws + 1056768);    //     8,192
  float* glog = (float*)(ws + 1196032);                        //       512
  int*   cnt  = (int*)  (ws + 1196544);                        //       512
  float* mass = (float*)(ws + 1197056);                        //       512
  float* conf = (float*)(ws + 1197568);                        //       512
  int*   bidx = (int*)  (ws + 1198080);                        // 2,097,152
  float* bw   = (float*)(ws + 3295232);                        // 2,097,152
  unsigned short* tok_bf = (unsigned short*)(ws + 5392384);    // 33,554,432
  float* gpart = (float*)(ws + 38946816);                      // 4,194,304

  k0_prep<<<256, 256, 0, stream>>>(W1, Wg, geno, Wgg, bgg, W1swz, Wgp_hi, Wgp_lo,
                                   cnt, mass, conf, glog);
  k1_gate<<<1024, 256, 0, stream>>>(tokens, Wgp_hi, Wgp_lo, bg, glog,
                                    cnt, bidx, bw, mass, conf, tok_bf);
  k4_expert<<<4096, 256, 0, stream>>>(tok_bf, W1swz, b1, cnt, bidx, bw, gpart);
  k5_centers<<<dim3(128, 2), 256, 0, stream>>>(gpart, cnt, W2, b2, mass, conf, out);
}

// Round 6
// 178.660 us; speedup vs baseline: 1.0156x; 1.0156x over previous
//
#include <hip/hip_runtime.h>

#define B_ 16
#define N_ 4096
#define C_ 256
#define K_ 8
#define EPS 1e-6f
#define RATIO 0.1f

typedef float f32x4 __attribute__((ext_vector_type(4)));
typedef __bf16 bf16x8 __attribute__((ext_vector_type(8)));

__device__ inline unsigned short f2bf(float f){
  unsigned int u = __float_as_uint(f);
  u += 0x7FFFu + ((u >> 16) & 1u);   // RNE
  return (unsigned short)(u >> 16);
}
__device__ inline float bf2f(unsigned short h){
  return __uint_as_float(((unsigned int)h) << 16);
}

union BFu { ushort4 u4[2]; bf16x8 v; };

// ---------------- K0: init ws, W1 -> frag-swizzled bf16, Wg hi/lo, geno logits
// W1swz flat index: (((k*16 + nt)*8 + s)*64 + lane)*8 + e
//   holds W1[k][nt*16 + (lane&15)][s*32 + (lane>>4)*8 + e]
__global__ __launch_bounds__(256) void k0_prep(
    const float* __restrict__ W1, const float* __restrict__ Wg,
    const float* __restrict__ geno, const float* __restrict__ Wgg,
    const float* __restrict__ bgg,
    unsigned short* __restrict__ W1swz,
    unsigned short* __restrict__ Wgp_hi, unsigned short* __restrict__ Wgp_lo,
    int* __restrict__ cnt,
    float* __restrict__ mass, float* __restrict__ conf,
    float* __restrict__ glog)
{
  int gid = blockIdx.x * 256 + threadIdx.x;           // 65536 threads
  if (gid < B_*K_) { cnt[gid] = 0; mass[gid] = 0.f; }
  if (gid == 0) conf[0] = 0.f;
  {
    int o = gid << 3;                                  // 8 elements per thread
    int lane6 = (o >> 3) & 63;
    int s  = (o >> 9) & 7;
    int nt = (o >> 12) & 15;
    int k  = o >> 16;
    int quad = lane6 >> 4, l16 = lane6 & 15;
    int j  = nt*16 + l16;
    int c0 = s*32 + quad*8;
    const float* src = W1 + (k << 16) + (j << 8) + c0;
    unsigned short* dst = W1swz + o;
    #pragma unroll
    for (int e = 0; e < 8; ++e) dst[e] = f2bf(src[e]);
  }
  if (gid < 16*C_){
    int r = gid >> 8, c = gid & 255;
    float v = (r < K_) ? Wg[(r << 8) + c] : 0.f;
    unsigned short h = f2bf(v);
    Wgp_hi[gid] = h;
    Wgp_lo[gid] = f2bf(v - bf2f(h));
  }
  int wv = gid >> 6;
  if (wv < B_*K_){
    int lane = threadIdx.x & 63;
    int b = wv >> 3, k = wv & 7;
    float4 a = *(const float4*)(geno + b*C_ + lane*4);
    float4 w = *(const float4*)(Wgg  + k*C_ + lane*4);
    float p = a.x*w.x + a.y*w.y + a.z*w.z + a.w*w.w;
    #pragma unroll
    for (int off = 32; off; off >>= 1) p += __shfl_xor(p, off);
    if (lane == 0) glog[wv] = RATIO * (p + bgg[k]);
  }
}

// ---------------- K1 (R13): asm-pinned hoisted loads (ext-vector types),
//                  4-wave phase-2 ---------------------------------------------
__global__ __launch_bounds__(256) void k1_gate(
    const float* __restrict__ tokens,
    const unsigned short* __restrict__ Wgp_hi, const unsigned short* __restrict__ Wgp_lo,
    const float* __restrict__ bg, const float* __restrict__ glog,
    int* __restrict__ cnt, int* __restrict__ bidx, float* __restrict__ bw,
    float* __restrict__ mass, float* __restrict__ conf,
    unsigned short* __restrict__ tok_bf)
{
  __shared__ float ls[64][9];              // logits, +1 pad
  __shared__ float bg_s[K_], gl_s[K_], mass_s[K_];
  __shared__ int lcnt[K_], gbase[K_];
  __shared__ int e0s[64], e1s[64], s0s[64], s1s[64];
  __shared__ float w0s[64], w1s[64];
  __shared__ float cred[4];
  int tid = threadIdx.x, lane = tid & 63, wave = tid >> 6;
  int quad = lane >> 4, l16 = lane & 15;
  int b = blockIdx.x >> 6;
  int tok0 = (blockIdx.x & 63) * 64;
  if (tid < K_){ bg_s[tid] = bg[tid]; gl_s[tid] = glog[b*K_ + tid];
                 mass_s[tid] = 0.f; lcnt[tid] = 0; }
  __syncthreads();

  // phase 1: logits via 3-term split-precision MFMA; emit bf16 tokens.
  // ALL 16 token loads issued before first wait, pinned by empty asm uses on
  // ext-vector (asm-legal) types; plain hoisting re-sank (VGPR=20 in R3).
  {
    int trow = tok0 + wave*16 + l16;
    const float* xsrc = tokens + ((size_t)b*N_ + trow)*C_ + quad*8;
    unsigned short* bdst = tok_bf + (((size_t)(b*N_ + trow)) << 8) + quad*8;
    f32x4 xa[8], xb[8];
    #pragma unroll
    for (int s = 0; s < 8; ++s){
      xa[s] = *(const f32x4*)(xsrc + s*32);
      xb[s] = *(const f32x4*)(xsrc + s*32 + 4);
    }
    asm volatile("" : "+v"(xa[0]), "+v"(xa[1]), "+v"(xa[2]), "+v"(xa[3]),
                      "+v"(xa[4]), "+v"(xa[5]), "+v"(xa[6]), "+v"(xa[7]));
    asm volatile("" : "+v"(xb[0]), "+v"(xb[1]), "+v"(xb[2]), "+v"(xb[3]),
                      "+v"(xb[4]), "+v"(xb[5]), "+v"(xb[6]), "+v"(xb[7]));
    f32x4 acc; acc.x = 0.f; acc.y = 0.f; acc.z = 0.f; acc.w = 0.f;
    #pragma unroll
    for (int s = 0; s < 8; ++s){
      BFu hi, lo;
      hi.u4[0].x = f2bf(xa[s][0]); hi.u4[0].y = f2bf(xa[s][1]);
      hi.u4[0].z = f2bf(xa[s][2]); hi.u4[0].w = f2bf(xa[s][3]);
      hi.u4[1].x = f2bf(xb[s][0]); hi.u4[1].y = f2bf(xb[s][1]);
      hi.u4[1].z = f2bf(xb[s][2]); hi.u4[1].w = f2bf(xb[s][3]);
      lo.u4[0].x = f2bf(xa[s][0] - bf2f(hi.u4[0].x));
      lo.u4[0].y = f2bf(xa[s][1] - bf2f(hi.u4[0].y));
      lo.u4[0].z = f2bf(xa[s][2] - bf2f(hi.u4[0].z));
      lo.u4[0].w = f2bf(xa[s][3] - bf2f(hi.u4[0].w));
      lo.u4[1].x = f2bf(xb[s][0] - bf2f(hi.u4[1].x));
      lo.u4[1].y = f2bf(xb[s][1] - bf2f(hi.u4[1].y));
      lo.u4[1].z = f2bf(xb[s][2] - bf2f(hi.u4[1].z));
      lo.u4[1].w = f2bf(xb[s][3] - bf2f(hi.u4[1].w));
      *(ushort4*)(bdst + s*32)     = hi.u4[0];
      *(ushort4*)(bdst + s*32 + 4) = hi.u4[1];
      bf16x8 bhi = *(const bf16x8*)(Wgp_hi + l16*C_ + s*32 + quad*8);
      bf16x8 blo = *(const bf16x8*)(Wgp_lo + l16*C_ + s*32 + quad*8);
      acc = __builtin_amdgcn_mfma_f32_16x16x32_bf16(hi.v, bhi, acc, 0, 0, 0);
      acc = __builtin_amdgcn_mfma_f32_16x16x32_bf16(lo.v, bhi, acc, 0, 0, 0);
      acc = __builtin_amdgcn_mfma_f32_16x16x32_bf16(hi.v, blo, acc, 0, 0, 0);
    }
    if (l16 < K_){
      #pragma unroll
      for (int rr = 0; rr < 4; ++rr){
        int tl = wave*16 + quad*4 + rr;     // D row = quad*4+reg
        ls[tl][l16] = acc[rr] + bg_s[l16] + gl_s[l16];
      }
    }
  }
  __syncthreads();

  // phase 2: per-token top-2 + softmax + compaction, PARALLEL across 4 waves
  if (quad == 0){
    int t = (wave << 4) | l16;
    float v0 = -1e30f, v1 = -1e30f; int i0 = 0, i1 = 0;
    #pragma unroll
    for (int kk = 0; kk < K_; ++kk){
      float l = ls[t][kk];
      if (l > v0){ v1 = v0; i1 = i0; v0 = l; i0 = kk; }
      else if (l > v1){ v1 = l; i1 = kk; }
    }
    float e  = expf(v1 - v0);
    float w0 = 1.f / (1.f + e), w1 = e / (1.f + e);
    w0 = fmaxf(w0, EPS); w1 = fmaxf(w1, EPS);
    float inv = 1.f / (w0 + w1);
    w0 *= inv; w1 *= inv;
    int p0 = atomicAdd(&lcnt[i0], 1);
    int p1 = atomicAdd(&lcnt[i1], 1);
    e0s[t] = i0; e1s[t] = i1; s0s[t] = p0; s1s[t] = p1;
    w0s[t] = w0; w1s[t] = w1;
    atomicAdd(&mass_s[i0], w0);
    atomicAdd(&mass_s[i1], w1);
    float ca = v0 - v1;                    // reduce over 16 active lanes
    #pragma unroll
    for (int off = 8; off; off >>= 1) ca += __shfl_down(ca, off);
    if (l16 == 0) cred[wave] = ca;
  }
  __syncthreads();
  if (tid < K_){                            // one global RMW per expert per block
    gbase[tid] = atomicAdd(&cnt[b*K_ + tid], lcnt[tid]);
    atomicAdd(&mass[b*K_ + tid], mass_s[tid]);
  }
  if (tid == 0) atomicAdd(conf, cred[0] + cred[1] + cred[2] + cred[3]);
  __syncthreads();
  if (quad == 0){
    int t = (wave << 4) | l16;
    int n = tok0 + t;
    int ke0 = e0s[t], ke1 = e1s[t];
    size_t o0 = (size_t)(b*K_ + ke0)*N_ + gbase[ke0] + s0s[t];
    size_t o1 = (size_t)(b*K_ + ke1)*N_ + gbase[ke1] + s1s[t];
    bidx[o0] = n;  bw[o0] = w0s[t];
    bidx[o1] = n;  bw[o1] = w1s[t];
  }
}

// ---------------- K4 (R13 = R12): DENSE work queue -> zero dead blocks -------
// R2/R3 grids were 4096 blocks but avg M~1024 => 75% exited instantly, mixing
// dead blocks into the dispatch stream (measured Occupancy 19%, ~1.5 active
// blocks/CU vs 4 allowed). Now: grid = 1152 (worst-case total chunks =
// 16*(8192/128 + 8)); every block recomputes the chunk-prefix over 128 buckets
// from cnt (one wave, ~50cy) and maps a DENSE work-id -> (bucket,chunk) via
// 7-step binary search. 4-region ring (32 KB) keeps 4 blocks/CU; depth-2
// counted-vmcnt pipeline (T3/T4) unchanged from R3.
#define K4_STAGE(T, REG) do {                                                  \
    _Pragma("unroll")                                                          \
    for (int i = 0; i < 2; ++i){                                               \
      int c16 = (T)*512 + i*256 + tid;                                         \
      __builtin_amdgcn_global_load_lds(                                        \
        (const __attribute__((address_space(1))) unsigned int*)(wsrc + c16*8), \
        (__attribute__((address_space(3))) unsigned int*)(&Bs[REG][0] + (i*256 + tid)*8), \
        16, 0, 0);                                                             \
    }                                                                          \
  } while(0)

__global__ __launch_bounds__(256, 4) void k4_expert(
    const unsigned short* __restrict__ tok_bf, const unsigned short* __restrict__ W1swz,
    const float* __restrict__ b1, const int* __restrict__ cnt,
    const int* __restrict__ bidx, const float* __restrict__ bw,
    float* __restrict__ gpart)
{
  __shared__ unsigned short Bs[4][4096];   // 32 KB: 4-region ring, 8 KB tiles
  __shared__ float wtok[128];
  __shared__ float red[2][4][16];
  __shared__ int Pb[129];

  int tid = threadIdx.x, lane = tid & 63, wave = tid >> 6;
  int quad = lane >> 4, l16 = lane & 15;

  if (wave == 0){                          // exclusive chunk-prefix, 2 buckets/lane
    int b2i = lane << 1;
    int cA = (cnt[b2i] + 127) >> 7;
    int cB = (cnt[b2i + 1] + 127) >> 7;
    int s = cA + cB;
    int ps = s;
    #pragma unroll
    for (int off = 1; off < 64; off <<= 1){
      int t = __shfl_up(ps, off);
      if (lane >= off) ps += t;
    }
    Pb[b2i]     = ps - s;
    Pb[b2i + 1] = ps - cB;
    if (lane == 63) Pb[128] = ps;
  }
  __syncthreads();

  int T = Pb[128];
  int lin = blockIdx.x;                    // 0..1151; XCD-contiguous work ranges
  int wq = (lin & 7) * 144 + (lin >> 3);
  if (wq >= T) return;                     // whole-block uniform exit
  int lo = 0, hi = 128;
  #pragma unroll
  for (int it = 0; it < 7; ++it){          // Pb[lo] <= wq < Pb[hi]
    int mid = (lo + hi) >> 1;
    if (Pb[mid] <= wq) lo = mid; else hi = mid;
  }
  int bucket = lo;
  int chunk = wq - Pb[lo];
  int bat = bucket >> 3, k = bucket & 7;
  int M = cnt[bucket];
  int Mm1 = M - 1;
  int bwbase = bucket << 12;               // bucket * N_

  const unsigned short* wsrc = W1swz + ((size_t)k << 16);

  // prologue: stage tiles 0,1
  K4_STAGE(0, 0);
  K4_STAGE(1, 1);

  if (tid < 128){
    int tn = chunk*128 + tid;
    wtok[tid] = (tn < M) ? bw[bwbase + tn] : 0.f;
  }

  // gather A fragments once; reused across all 16 tiles
  int r0 = chunk*128 + (wave << 4) + l16;
  int nn0 = bidx[bwbase + min(r0, Mm1)];
  int nn1 = bidx[bwbase + min(r0 + 64, Mm1)];
  const unsigned short* p0 = tok_bf + (((size_t)((bat << 12) + nn0)) << 8) + (quad << 3);
  const unsigned short* p1 = tok_bf + (((size_t)((bat << 12) + nn1)) << 8) + (quad << 3);
  bf16x8 a0[8], a1[8];
  #pragma unroll
  for (int s = 0; s < 8; ++s){
    a0[s] = *(const bf16x8*)(p0 + s*32);
    a1[s] = *(const bf16x8*)(p1 + s*32);
  }

  float bias[16];
  #pragma unroll
  for (int p = 0; p < 16; ++p) bias[p] = b1[(k << 8) + (p << 4) + l16];

  float* gdst = gpart + (size_t)(((bucket << 5) + chunk) << 8);
  int wq4 = (wave << 4) + (quad << 2);

  #pragma unroll
  for (int p = 0; p < 16; ++p){
    if (p < 14){
      K4_STAGE(p + 2, (p + 2) & 3);
      asm volatile("s_waitcnt vmcnt(4) lgkmcnt(0)" ::: "memory");
    } else if (p == 14){
      asm volatile("s_waitcnt vmcnt(2) lgkmcnt(0)" ::: "memory");
    } else {
      asm volatile("s_waitcnt vmcnt(0) lgkmcnt(0)" ::: "memory");
    }
    __builtin_amdgcn_s_barrier();

    if (p > 0 && tid < 16){                // tile p-1 cross-wave sum + store
      int pb = (p - 1) & 1;
      float sv = red[pb][0][tid] + red[pb][1][tid]
               + red[pb][2][tid] + red[pb][3][tid];
      gdst[((p - 1) << 4) + tid] = sv;
    }

    f32x4 acc0, acc1;
    acc0.x=0.f; acc0.y=0.f; acc0.z=0.f; acc0.w=0.f;
    acc1.x=0.f; acc1.y=0.f; acc1.z=0.f; acc1.w=0.f;
    #pragma unroll
    for (int s = 0; s < 8; ++s){
      bf16x8 bb = *(const bf16x8*)(&Bs[p & 3][0] + ((s*64 + lane) << 3));
      acc0 = __builtin_amdgcn_mfma_f32_16x16x32_bf16(a0[s], bb, acc0, 0, 0, 0);
      acc1 = __builtin_amdgcn_mfma_f32_16x16x32_bf16(a1[s], bb, acc1, 0, 0, 0);
    }
    float pt = 0.f;
    #pragma unroll
    for (int rr = 0; rr < 4; ++rr){
      float h0 = fmaxf(acc0[rr] + bias[p], 0.f);
      float h1 = fmaxf(acc1[rr] + bias[p], 0.f);
      pt += wtok[wq4 + rr] * h0 + wtok[64 + wq4 + rr] * h1;
    }
    pt += __shfl_down(pt, 32);
    pt += __shfl_down(pt, 16);
    if (lane < 16) red[p & 1][wave][lane] = pt;
  }
  asm volatile("s_waitcnt lgkmcnt(0)" ::: "memory");
  __builtin_amdgcn_s_barrier();
  if (tid < 16){                           // tail: tile 15
    float sv = red[1][0][tid] + red[1][1][tid] + red[1][2][tid] + red[1][3][tid];
    gdst[(15 << 4) + tid] = sv;
  }
}

// ---------------- K5: reduce chunk partials + layer-2 + divide by mass
//                  (+ fused scalars: lb_loss & routing confidence) -----------
__global__ __launch_bounds__(256) void k5_centers(
    const float* __restrict__ gpart, const int* __restrict__ cnt,
    const float* __restrict__ W2, const float* __restrict__ b2,
    const float* __restrict__ mass, const float* __restrict__ conf,
    float* __restrict__ out)
{
  __shared__ float gv[C_];
  int z = blockIdx.x, tid = threadIdx.x;
  int k = z & 7;
  int nch = (cnt[z] + 127) >> 7;
  float sv = 0.f;
  for (int c = 0; c < nch; ++c)
    sv += gpart[(size_t)((((z << 5) + c) << 8) + tid)];
  gv[tid] = sv;
  __syncthreads();
  float m = mass[z];
  float inv = 1.f / fmaxf(m, EPS);
  int tq = tid & 3, cb = tid >> 2;
  #pragma unroll 1
  for (int h = 0; h < 2; ++h){
    int c = (blockIdx.y*2 + h)*64 + cb;
    const float4* wrow = (const float4*)(W2 + ((((k << 8) + c)) << 8));
    float dot = 0.f;
    #pragma unroll
    for (int jj = 0; jj < 16; ++jj){
      float4 w4 = wrow[jj*4 + tq];
      float4 g4 = *(const float4*)&gv[(jj*4 + tq) * 4];
      dot += w4.x*g4.x + w4.y*g4.y + w4.z*g4.z + w4.w*g4.w;
    }
    dot += __shfl_xor(dot, 1);
    dot += __shfl_xor(dot, 2);
    if (tq == 0) out[z*C_ + c] = (dot + m * b2[k*C_ + c]) * inv;
  }
  if (z == 0 && blockIdx.y == 0 && tid == 0){   // fused k2 (single thread)
    float u[K_];
    #pragma unroll
    for (int kk = 0; kk < K_; ++kk) u[kk] = 0.f;
    for (int i = 0; i < B_*K_; ++i) u[i & 7] += (float)cnt[i];
    float mean = 0.f;
    #pragma unroll
    for (int kk = 0; kk < K_; ++kk){ u[kk] *= (1.f / (float)(B_*N_)); mean += u[kk]; }
    mean *= (1.f / K_);
    float var = 0.f;
    #pragma unroll
    for (int kk = 0; kk < K_; ++kk){ float d = u[kk] - mean; var += d*d; }
    var *= (1.f / K_);
    float denom = mean + EPS;
    out[B_*K_*C_]     = var / (denom * denom);
    out[B_*K_*C_ + 1] = conf[0] / (float)(B_*N_);
  }
}

extern "C" void kernel_launch(void* const* d_in, const int* in_sizes, int n_in,
                              void* d_out, int out_size, void* d_ws, size_t ws_size,
                              hipStream_t stream)
{
  const float* tokens = (const float*)d_in[0];
  const float* geno   = (const float*)d_in[1];
  const float* Wg     = (const float*)d_in[2];
  const float* bg     = (const float*)d_in[3];
  const float* Wgg    = (const float*)d_in[4];
  const float* bgg    = (const float*)d_in[5];
  const float* W1     = (const float*)d_in[6];
  const float* b1     = (const float*)d_in[7];
  const float* W2     = (const float*)d_in[8];
  const float* b2     = (const float*)d_in[9];
  float* out = (float*)d_out;
  char* ws = (char*)d_ws;
  unsigned short* W1swz  = (unsigned short*)(ws);              // 1,048,576
  unsigned short* Wgp_hi = (unsigned short*)(ws + 1048576);    //     8,192
  unsigned short* Wgp_lo = (unsigned short*)(ws + 1056768);    //     8,192
  float* glog = (float*)(ws + 1196032);                        //       512
  int*   cnt  = (int*)  (ws + 1196544);                        //       512
  float* mass = (float*)(ws + 1197056);                        //       512
  float* conf = (float*)(ws + 1197568);                        //       512
  int*   bidx = (int*)  (ws + 1198080);                        // 2,097,152
  float* bw   = (float*)(ws + 3295232);                        // 2,097,152
  unsigned short* tok_bf = (unsigned short*)(ws + 5392384);    // 33,554,432
  float* gpart = (float*)(ws + 38946816);                      // 4,194,304

  k0_prep<<<256, 256, 0, stream>>>(W1, Wg, geno, Wgg, bgg, W1swz, Wgp_hi, Wgp_lo,
                                   cnt, mass, conf, glog);
  k1_gate<<<1024, 256, 0, stream>>>(tokens, Wgp_hi, Wgp_lo, bg, glog,
                                    cnt, bidx, bw, mass, conf, tok_bf);
  k4_expert<<<1152, 256, 0, stream>>>(tok_bf, W1swz, b1, cnt, bidx, bw, gpart);
  k5_centers<<<dim3(128, 2), 256, 0, stream>>>(gpart, cnt, W2, b2, mass, conf, out);
}